// Round 7
// baseline (684.543 us; speedup 1.0000x reference)
//
#include <hip/hip_runtime.h>

#define Bsz 512
#define Ssz 512
#define Isz 32
#define Hsz 128
#define BB  2
#define NT  512   // 8 waves, 2 per SIMD
#define LOG2E 1.44269504088896340736f

typedef __attribute__((ext_vector_type(8))) short bf16x8;
typedef __attribute__((ext_vector_type(4))) float f32x4;

__device__ __forceinline__ unsigned short f2bf(float f){
  unsigned u = __float_as_uint(f);
  return (unsigned short)((u + 0x7FFFu + ((u >> 16) & 1u)) >> 16);
}
__device__ __forceinline__ float sigm_p(float xp){          // pre-scaled by log2e
  return __builtin_amdgcn_rcpf(1.f + __builtin_amdgcn_exp2f(-xp));
}
__device__ __forceinline__ float tanh_p(float xp2){         // pre-scaled by 2*log2e
  return 1.f - 2.f * __builtin_amdgcn_rcpf(1.f + __builtin_amdgcn_exp2f(xp2));
}
__device__ __forceinline__ bf16x8 ldw(const float* p, float s){
  bf16x8 r;
#pragma unroll
  for (int e=0;e<8;++e) r[e] = (short)f2bf(p[e]*s);
  return r;
}
__device__ __forceinline__ bf16x8 ldws(const float* pa, const float* pb, float s){
  bf16x8 r;
#pragma unroll
  for (int e=0;e<8;++e) r[e] = (short)f2bf((pa[e]+pb[e])*s);
  return r;
}

__global__ __launch_bounds__(NT, 2) void lstm_ae(
    const float* __restrict__ x,
    const float* __restrict__ eWih, const float* __restrict__ eWhh,
    const float* __restrict__ ebih, const float* __restrict__ ebhh,
    const float* __restrict__ dWih, const float* __restrict__ dWhh,
    const float* __restrict__ dbih, const float* __restrict__ dbhh,
    const float* __restrict__ fcW,  const float* __restrict__ fcb,
    float* __restrict__ out)
{
  __shared__ __attribute__((aligned(16))) float big[2*Ssz*Isz];   // x bf16 / frames f32
  __shared__ __attribute__((aligned(16))) unsigned short hbuf[2][2][136];
  __shared__ unsigned cnt[2][4];      // per-buffer, per-chunk monotonic publish counters

  const int tid  = threadIdx.x;
  const int lane = tid & 63;
  const int wv   = tid >> 6;          // owns cols 16wv..16wv+15, all 4 gates
  const int c16  = lane & 15;
  const int quad = lane >> 4;
  const int bg0  = blockIdx.x * BB;
  const int hrow = (c16 >> 2) & 1;    // batch rows at A-rows 0/4 -> C rows 0(q0),4(q1)
  const int col  = wv*16 + c16;
  const int myc  = wv >> 1;           // chunk this wave co-publishes

  // ---- stage x as bf16 into LDS ----
  unsigned short* xl = (unsigned short*)big;
#pragma unroll 2
  for (int i = tid*4; i < 2*Ssz*Isz; i += NT*4){
    f32x4 v = *(const f32x4*)(x + (size_t)(bg0 + (i>>14))*(Ssz*Isz) + (i & 16383));
    xl[i+0]=f2bf(v[0]); xl[i+1]=f2bf(v[1]); xl[i+2]=f2bf(v[2]); xl[i+3]=f2bf(v[3]);
  }
  for (int i = tid; i < 2*2*136; i += NT) ((unsigned short*)hbuf)[i] = 0;
  if (tid < 8) ((unsigned*)cnt)[tid] = 0;

  // per-wave chunk order: own chunk first (slot m -> chunk (myc+m)&3)
  const unsigned short* rp0[4];
  const unsigned short* rp1[4];
  int cperm[4];
#pragma unroll
  for (int m=0;m<4;++m){
    cperm[m] = (myc+m)&3;
    rp0[m] = &hbuf[0][hrow][0] + cperm[m]*32 + quad*8;
    rp1[m] = &hbuf[1][hrow][0] + cperm[m]*32 + quad*8;
  }
  unsigned short* wr0 = &hbuf[1][quad&1][col];   // write target when reading buf0
  unsigned short* wr1 = &hbuf[0][quad&1][col];

  // ---- encoder weights -> registers (slot-permuted) ----
  bf16x8 W[4][4], wx[4];
#pragma unroll
  for (int g=0;g<4;++g){
    int n = g*128 + col;
    float s = (g==2) ? 2.f*LOG2E : LOG2E;
#pragma unroll
    for (int m=0;m<4;++m) W[g][m] = ldw(eWhh + (size_t)n*Hsz + cperm[m]*32 + quad*8, s);
    wx[g] = ldw(eWih + (size_t)n*Isz + quad*8, s);
  }
  float b_i = (ebih[0*Hsz+col]+ebhh[0*Hsz+col])*LOG2E;
  float b_f = (ebih[1*Hsz+col]+ebhh[1*Hsz+col])*LOG2E;
  float b_g = (ebih[2*Hsz+col]+ebhh[2*Hsz+col])*(2.f*LOG2E);
  float b_o = (ebih[3*Hsz+col]+ebhh[3*Hsz+col])*LOG2E;

  const f32x4 zero4 = {0.f,0.f,0.f,0.f};
  float cst = 0.f;

  auto act = [&](const f32x4* acc, unsigned short* wp, bool upd){
    if (quad < 2){
      float pi = acc[0][0] + b_i;
      float pf = acc[1][0] + b_f;
      float pg = acc[2][0] + b_g;
      float po = acc[3][0] + b_o;
      float iv=sigm_p(pi), fv=sigm_p(pf), ov=sigm_p(po), gv=tanh_p(pg);
      float cn = fv*cst + iv*gv;
      if (upd) cst = cn;
      *wp = f2bf(ov * tanh_p(cn*(2.f*LOG2E)));
    }
  };
  auto publish = [&](unsigned* cq){
    if (lane == 0)
      __hip_atomic_fetch_add(&cq[myc], 1u, __ATOMIC_RELEASE, __HIP_MEMORY_SCOPE_WORKGROUP);
  };

  __syncthreads();   // x staged, hbuf[0] + counters zeroed

  // ---------------- encoder ----------------
  // ebody: poll chunks as needed, 16 gate MFMAs, act, publish, then next-x prep
  auto ebody = [&](const unsigned short* const* rp, unsigned short* wp,
                   unsigned* cpoll, unsigned* cpub, unsigned rq, bool doPoll,
                   f32x4* acc, f32x4* acc2, bf16x8& axn, const unsigned short*& xp){
    bf16x8 a[4];
#pragma unroll
    for (int m=0;m<4;++m){
      if (doPoll){
        while (__hip_atomic_load(&cpoll[cperm[m]], __ATOMIC_ACQUIRE, __HIP_MEMORY_SCOPE_WORKGROUP) < rq) {}
      }
      a[m] = *(const bf16x8*)rp[m];
#pragma unroll
      for (int g=0;g<4;++g)
        acc[g] = __builtin_amdgcn_mfma_f32_16x16x32_bf16(a[m], W[g][m], acc[g], 0,0,0);
    }
    act(acc, wp, true);
    publish(cpub);
    // next step's x contribution (off critical path)
#pragma unroll
    for (int g=0;g<4;++g) acc2[g] = __builtin_amdgcn_mfma_f32_16x16x32_bf16(axn, wx[g], zero4, 0,0,0);
    axn = *(const bf16x8*)xp; xp += 32;
  };

  const unsigned short* xq = xl + hrow*(Ssz*Isz) + quad*8;
  bf16x8 ax0 = *(const bf16x8*)(xq);
  bf16x8 axn = *(const bf16x8*)(xq + 32);
  const unsigned short* xp = xq + 64;
  f32x4 A_[4], B_[4];
#pragma unroll
  for (int g=0;g<4;++g) A_[g] = __builtin_amdgcn_mfma_f32_16x16x32_bf16(ax0, wx[g], zero4, 0,0,0);

  unsigned rq = 0;
  ebody(rp0, wr0, &cnt[0][0], &cnt[1][0], 0, false, A_, B_, axn, xp);   // ts=0
  for (int it=0; it<255; ++it){
    rq += 2;
    ebody(rp1, wr1, &cnt[1][0], &cnt[0][0], rq, true, B_, A_, axn, xp); // ts odd
    ebody(rp0, wr0, &cnt[0][0], &cnt[1][0], rq, true, A_, B_, axn, xp); // ts even
  }
  rq += 2;  // = 512
  ebody(rp1, wr1, &cnt[1][0], &cnt[0][0], rq, true, B_, A_, axn, xp);   // ts=511 -> h(511) in buf0

  // ---------------- decoder ----------------
  b_i = (dbih[0*Hsz+col]+dbhh[0*Hsz+col])*LOG2E;
  b_f = (dbih[1*Hsz+col]+dbhh[1*Hsz+col])*LOG2E;
  b_g = (dbih[2*Hsz+col]+dbhh[2*Hsz+col])*(2.f*LOG2E);
  b_o = (dbih[3*Hsz+col]+dbhh[3*Hsz+col])*LOG2E;

  // dec step 0 (ts=512): gates = enc_h @ dWhh^T + b (cell stays enc_c)
#pragma unroll
  for (int g=0;g<4;++g){
    int n = g*128 + col;
    float s = (g==2) ? 2.f*LOG2E : LOG2E;
#pragma unroll
    for (int m=0;m<4;++m) W[g][m] = ldw(dWhh + (size_t)n*Hsz + cperm[m]*32 + quad*8, s);
  }
  {
    bf16x8 a[4];
    f32x4 acc[4];
#pragma unroll
    for (int m=0;m<4;++m){
      while (__hip_atomic_load(&cnt[0][cperm[m]], __ATOMIC_ACQUIRE, __HIP_MEMORY_SCOPE_WORKGROUP) < rq) {}
      a[m] = *(const bf16x8*)rp0[m];
      if (m == 0){
#pragma unroll
        for (int g=0;g<4;++g) acc[g] = __builtin_amdgcn_mfma_f32_16x16x32_bf16(a[0], W[g][0], zero4, 0,0,0);
      } else {
#pragma unroll
        for (int g=0;g<4;++g) acc[g] = __builtin_amdgcn_mfma_f32_16x16x32_bf16(a[m], W[g][m], acc[g], 0,0,0);
      }
    }
    act(acc, wr0, false);
    publish(&cnt[1][0]);
  }

  // steps >=1: W = (dWih + dWhh); fc on waves 6,7 (after publish, off critical path)
#pragma unroll
  for (int g=0;g<4;++g){
    int n = g*128 + col;
    float s = (g==2) ? 2.f*LOG2E : LOG2E;
#pragma unroll
    for (int m=0;m<4;++m){
      const float* pa = dWih + (size_t)n*Hsz + cperm[m]*32 + quad*8;
      const float* pb = dWhh + (size_t)n*Hsz + cperm[m]*32 + quad*8;
      W[g][m] = ldws(pa, pb, s);
    }
  }
  bf16x8 wf[4];
  f32x4 biasf4 = {0.f,0.f,0.f,0.f};
  if (wv >= 6){
    int n = (wv-6)*16 + c16;
#pragma unroll
    for (int m=0;m<4;++m) wf[m] = ldw(fcW + (size_t)n*Hsz + cperm[m]*32 + quad*8, 1.f);
    float bfc = fcb[n];
    biasf4[0]=bfc; biasf4[1]=bfc; biasf4[2]=bfc; biasf4[3]=bfc;
  }
  const int nf = (wv >= 6) ? (wv-6)*16 + c16 : 0;
  float* fp = big + quad*(Ssz*Isz) + nf;

  auto dbody = [&](const unsigned short* const* rp, unsigned short* wp,
                   unsigned* cpoll, unsigned* cpub, unsigned rqq, float*& fpp){
    bf16x8 a[4];
    f32x4 acc[4];
#pragma unroll
    for (int m=0;m<4;++m){
      while (__hip_atomic_load(&cpoll[cperm[m]], __ATOMIC_ACQUIRE, __HIP_MEMORY_SCOPE_WORKGROUP) < rqq) {}
      a[m] = *(const bf16x8*)rp[m];
      if (m == 0){
#pragma unroll
        for (int g=0;g<4;++g) acc[g] = __builtin_amdgcn_mfma_f32_16x16x32_bf16(a[0], W[g][0], zero4, 0,0,0);
      } else {
#pragma unroll
        for (int g=0;g<4;++g) acc[g] = __builtin_amdgcn_mfma_f32_16x16x32_bf16(a[m], W[g][m], acc[g], 0,0,0);
      }
    }
    act(acc, wp, false);
    publish(cpub);
    if (wv >= 6){
      f32x4 fa = __builtin_amdgcn_mfma_f32_16x16x32_bf16(a[0], wf[0], biasf4, 0,0,0);
      fa = __builtin_amdgcn_mfma_f32_16x16x32_bf16(a[1], wf[1], fa, 0,0,0);
      fa = __builtin_amdgcn_mfma_f32_16x16x32_bf16(a[2], wf[2], fa, 0,0,0);
      fa = __builtin_amdgcn_mfma_f32_16x16x32_bf16(a[3], wf[3], fa, 0,0,0);
      if (quad < 2) *fpp = fa[0];
    }
    fpp += 32;
  };

  // ts = 513..1022 in pairs (frame t-1 stored each body), then ts=1023
  for (int it=0; it<255; ++it){
    rq += 2;
    dbody(rp1, wr1, &cnt[1][0], &cnt[0][0], rq, fp);   // odd ts reads buf1
    dbody(rp0, wr0, &cnt[0][0], &cnt[1][0], rq, fp);   // even ts reads buf0
  }
  rq += 2;  // = 1024
  dbody(rp1, wr1, &cnt[1][0], &cnt[0][0], rq, fp);     // ts=1023 -> h(511) in buf0, frame 510

  // epilogue: frame 511 from h(511) (buf0; require all ts=1023 publishes)
  if (wv >= 6){
    bf16x8 a[4];
#pragma unroll
    for (int m=0;m<4;++m){
      while (__hip_atomic_load(&cnt[0][cperm[m]], __ATOMIC_ACQUIRE, __HIP_MEMORY_SCOPE_WORKGROUP) < rq) {}
      a[m] = *(const bf16x8*)rp0[m];
    }
    f32x4 fa = __builtin_amdgcn_mfma_f32_16x16x32_bf16(a[0], wf[0], biasf4, 0,0,0);
    fa = __builtin_amdgcn_mfma_f32_16x16x32_bf16(a[1], wf[1], fa, 0,0,0);
    fa = __builtin_amdgcn_mfma_f32_16x16x32_bf16(a[2], wf[2], fa, 0,0,0);
    fa = __builtin_amdgcn_mfma_f32_16x16x32_bf16(a[3], wf[3], fa, 0,0,0);
    if (quad < 2) *fp = fa[0];
  }
  __syncthreads();

  // bulk coalesced frame store
#pragma unroll 2
  for (int i = tid*4; i < 2*Ssz*Isz; i += NT*4){
    f32x4 v = *(const f32x4*)(big + i);
    *(f32x4*)(out + (size_t)(bg0 + (i>>14))*(Ssz*Isz) + (i & 16383)) = v;
  }
}

extern "C" void kernel_launch(void* const* d_in, const int* in_sizes, int n_in,
                              void* d_out, int out_size, void* d_ws, size_t ws_size,
                              hipStream_t stream) {
  const float* x    = (const float*)d_in[0];
  const float* eWih = (const float*)d_in[1];
  const float* eWhh = (const float*)d_in[2];
  const float* ebih = (const float*)d_in[3];
  const float* ebhh = (const float*)d_in[4];
  const float* dWih = (const float*)d_in[5];
  const float* dWhh = (const float*)d_in[6];
  const float* dbih = (const float*)d_in[7];
  const float* dbhh = (const float*)d_in[8];
  const float* fcW  = (const float*)d_in[9];
  const float* fcb  = (const float*)d_in[10];
  float* outp = (float*)d_out;
  (void)d_ws; (void)ws_size; (void)in_sizes; (void)n_in; (void)out_size;
  lstm_ae<<<dim3(Bsz/BB), dim3(NT), 0, stream>>>(
      x, eWih, eWhh, ebih, ebhh, dWih, dWhh, dbih, dbhh, fcW, fcb, outp);
}

// Round 9
// 667.830 us; speedup vs baseline: 1.0250x; 1.0250x over previous
//
#include <hip/hip_runtime.h>

#define Bsz 512
#define Ssz 512
#define Isz 32
#define Hsz 128
#define BB  2
#define NT  512   // 8 waves, 2 per SIMD
#define LOG2E 1.44269504088896340736f

typedef __attribute__((ext_vector_type(8))) short bf16x8;
typedef __attribute__((ext_vector_type(4))) float f32x4;
typedef __attribute__((ext_vector_type(4))) unsigned u32x4;

__device__ __forceinline__ unsigned short f2bf(float f){
  unsigned u = __float_as_uint(f);
  return (unsigned short)((u + 0x7FFFu + ((u >> 16) & 1u)) >> 16);
}
__device__ __forceinline__ float sigm_p(float xp){          // pre-scaled by log2e
  return __builtin_amdgcn_rcpf(1.f + __builtin_amdgcn_exp2f(-xp));
}
__device__ __forceinline__ float tanh_p(float xp2){         // pre-scaled by 2*log2e
  return 1.f - 2.f * __builtin_amdgcn_rcpf(1.f + __builtin_amdgcn_exp2f(xp2));
}
__device__ __forceinline__ bf16x8 ldw(const float* p, float s){
  bf16x8 r;
#pragma unroll
  for (int e=0;e<8;++e) r[e] = (short)f2bf(p[e]*s);
  return r;
}
__device__ __forceinline__ bf16x8 ldws(const float* pa, const float* pb, float s){
  bf16x8 r;
#pragma unroll
  for (int e=0;e<8;++e) r[e] = (short)f2bf((pa[e]+pb[e])*s);
  return r;
}
__device__ __forceinline__ unsigned umin2(unsigned a, unsigned b){ return a<b?a:b; }

__global__ __launch_bounds__(NT, 2) void lstm_ae(
    const float* __restrict__ x,
    const float* __restrict__ eWih, const float* __restrict__ eWhh,
    const float* __restrict__ ebih, const float* __restrict__ ebhh,
    const float* __restrict__ dWih, const float* __restrict__ dWhh,
    const float* __restrict__ dbih, const float* __restrict__ dbhh,
    const float* __restrict__ fcW,  const float* __restrict__ fcb,
    float* __restrict__ out)
{
  __shared__ __attribute__((aligned(16))) float big[2*Ssz*Isz];   // x bf16 / frames f32
  __shared__ __attribute__((aligned(16))) unsigned short hbuf[2][2][136];
  __shared__ __attribute__((aligned(16))) unsigned flg[2][4];     // monotonic publish counters

  const int tid  = threadIdx.x;
  const int lane = tid & 63;
  const int wv   = tid >> 6;          // owns cols 16wv..16wv+15, all 4 gates
  const int c16  = lane & 15;
  const int quad = lane >> 4;
  const int bg0  = blockIdx.x * BB;
  const int hrow = (c16 >> 2) & 1;    // batch rows at A-rows 0/4 -> C rows 0(q0),4(q1)
  const int col  = wv*16 + c16;

  // ---- stage x as bf16 into LDS ----
  unsigned short* xl = (unsigned short*)big;
#pragma unroll 2
  for (int i = tid*4; i < 2*Ssz*Isz; i += NT*4){
    f32x4 v = *(const f32x4*)(x + (size_t)(bg0 + (i>>14))*(Ssz*Isz) + (i & 16383));
    xl[i+0]=f2bf(v[0]); xl[i+1]=f2bf(v[1]); xl[i+2]=f2bf(v[2]); xl[i+3]=f2bf(v[3]);
  }
  for (int i = tid; i < 2*2*136; i += NT) ((unsigned short*)hbuf)[i] = 0;
  if (tid < 8) ((unsigned*)flg)[tid] = 0;

  // precomputed lane pointers
  const unsigned short* rd0 = &hbuf[0][hrow][0] + quad*8;
  const unsigned short* rd1 = &hbuf[1][hrow][0] + quad*8;
  unsigned short* wr0 = &hbuf[1][quad&1][col];   // write target when reading buf0
  unsigned short* wr1 = &hbuf[0][quad&1][col];
  const volatile unsigned* fb0 = &flg[0][0];
  const volatile unsigned* fb1 = &flg[1][0];
  unsigned* pub0 = &flg[1][wv>>1];   // publish after writing buf1 (a buf0-read step)
  unsigned* pub1 = &flg[0][wv>>1];

  // ---- encoder weights -> registers ----
  bf16x8 W[4][4], wx[4];
#pragma unroll
  for (int g=0;g<4;++g){
    int n = g*128 + col;
    float s = (g==2) ? 2.f*LOG2E : LOG2E;
#pragma unroll
    for (int m=0;m<4;++m) W[g][m] = ldw(eWhh + (size_t)n*Hsz + m*32 + quad*8, s);
    wx[g] = ldw(eWih + (size_t)n*Isz + quad*8, s);
  }
  float b_i = (ebih[0*Hsz+col]+ebhh[0*Hsz+col])*LOG2E;
  float b_f = (ebih[1*Hsz+col]+ebhh[1*Hsz+col])*LOG2E;
  float b_g = (ebih[2*Hsz+col]+ebhh[2*Hsz+col])*(2.f*LOG2E);
  float b_o = (ebih[3*Hsz+col]+ebhh[3*Hsz+col])*LOG2E;

  const f32x4 zero4 = {0.f,0.f,0.f,0.f};
  float cst = 0.f;

  auto rdflags = [&](const volatile unsigned* fb)->u32x4 {
    u32x4 r; r[0]=fb[0]; r[1]=fb[1]; r[2]=fb[2]; r[3]=fb[3]; return r;
  };
  auto fmin = [&](u32x4 f)->unsigned {
    return __builtin_amdgcn_readfirstlane(umin2(umin2(f[0],f[1]), umin2(f[2],f[3])));
  };
  // acquire: prefetched flag value was READ BEFORE the data reads below (prior
  // step), so fpre>=req proves publishes (and thus h-writes) precede our reads.
  auto waitflags = [&](const volatile unsigned* fb, u32x4 fpre, unsigned req){
    if (fmin(fpre) < req){
      u32x4 f;
      do { f = rdflags(fb); } while (fmin(f) < req);   // poll-THEN-read: correct order
    }
    asm volatile("" ::: "memory");   // keep data reads below the check
  };
  auto act = [&](const f32x4* acc, unsigned short* wp, bool upd){
    if (quad < 2){
      float pi = acc[0][0] + b_i;
      float pf = acc[1][0] + b_f;
      float pg = acc[2][0] + b_g;
      float po = acc[3][0] + b_o;
      float iv=sigm_p(pi), fv=sigm_p(pf), ov=sigm_p(po), gv=tanh_p(pg);
      float cn = fv*cst + iv*gv;
      if (upd) cst = cn;
      *wp = f2bf(ov * tanh_p(cn*(2.f*LOG2E)));
    }
  };
  auto publish = [&](unsigned* pub){
    if (lane == 0)
      __hip_atomic_fetch_add(pub, 1u, __ATOMIC_RELEASE, __HIP_MEMORY_SCOPE_WORKGROUP);
  };

  __syncthreads();   // x staged, hbuf/flags zeroed

  // ---------------- encoder ----------------
  auto ebody = [&](const unsigned short* rd, const volatile unsigned* fbT, u32x4 fpre, unsigned req,
                   unsigned short* wp, unsigned* pub, const volatile unsigned* fbN,
                   f32x4* acc, f32x4* acc2, bf16x8& axn, const unsigned short*& xp)->u32x4 {
    waitflags(fbT, fpre, req);
    bf16x8 a0 = *(const bf16x8*)(rd);
    bf16x8 a1 = *(const bf16x8*)(rd+32);
    bf16x8 a2 = *(const bf16x8*)(rd+64);
    bf16x8 a3 = *(const bf16x8*)(rd+96);
#pragma unroll
    for (int g=0;g<4;++g) acc[g] = __builtin_amdgcn_mfma_f32_16x16x32_bf16(a0, W[g][0], acc[g], 0,0,0);
#pragma unroll
    for (int g=0;g<4;++g) acc[g] = __builtin_amdgcn_mfma_f32_16x16x32_bf16(a1, W[g][1], acc[g], 0,0,0);
#pragma unroll
    for (int g=0;g<4;++g) acc[g] = __builtin_amdgcn_mfma_f32_16x16x32_bf16(a2, W[g][2], acc[g], 0,0,0);
#pragma unroll
    for (int g=0;g<4;++g) acc[g] = __builtin_amdgcn_mfma_f32_16x16x32_bf16(a3, W[g][3], acc[g], 0,0,0);
    act(acc, wp, true);
    publish(pub);
    // off-critical-path extras: next-x MFMA, x prefetch, next-step flag prefetch
#pragma unroll
    for (int g=0;g<4;++g) acc2[g] = __builtin_amdgcn_mfma_f32_16x16x32_bf16(axn, wx[g], zero4, 0,0,0);
    axn = *(const bf16x8*)xp; xp += 32;
    return rdflags(fbN);
  };

  const unsigned short* xq = xl + hrow*(Ssz*Isz) + quad*8;
  bf16x8 ax0 = *(const bf16x8*)(xq);
  bf16x8 axn = *(const bf16x8*)(xq + 32);
  const unsigned short* xp = xq + 64;
  f32x4 A_[4], B_[4];
#pragma unroll
  for (int g=0;g<4;++g) A_[g] = __builtin_amdgcn_mfma_f32_16x16x32_bf16(ax0, wx[g], zero4, 0,0,0);

  u32x4 fA = {0,0,0,0}, fB = {0,0,0,0};
  unsigned e = 0;
  for (int it=0; it<256; ++it){              // ts = 2it (buf0), 2it+1 (buf1)
    fB = ebody(rd0, fb0, fA, e,   wr0, pub0, fb1, A_, B_, axn, xp);
    fA = ebody(rd1, fb1, fB, e+2, wr1, pub1, fb0, B_, A_, axn, xp);
    e += 2;
  }                                          // e = 512; h(511) in buf0

  // ---------------- decoder ----------------
  b_i = (dbih[0*Hsz+col]+dbhh[0*Hsz+col])*LOG2E;
  b_f = (dbih[1*Hsz+col]+dbhh[1*Hsz+col])*LOG2E;
  b_g = (dbih[2*Hsz+col]+dbhh[2*Hsz+col])*(2.f*LOG2E);
  b_o = (dbih[3*Hsz+col]+dbhh[3*Hsz+col])*LOG2E;

  bf16x8 wf[4];
  f32x4 biasf4 = {0.f,0.f,0.f,0.f};
  if (wv >= 6){
    int n = (wv-6)*16 + c16;
#pragma unroll
    for (int m=0;m<4;++m) wf[m] = ldw(fcW + (size_t)n*Hsz + m*32 + quad*8, 1.f);
    float bfc = fcb[n];
    biasf4[0]=bfc; biasf4[1]=bfc; biasf4[2]=bfc; biasf4[3]=bfc;
  }

  // dec step 0: gates = enc_h @ dWhh^T + b (cell stays enc_c; no frame)
#pragma unroll
  for (int g=0;g<4;++g){
    int n = g*128 + col;
    float s = (g==2) ? 2.f*LOG2E : LOG2E;
#pragma unroll
    for (int m=0;m<4;++m) W[g][m] = ldw(dWhh + (size_t)n*Hsz + m*32 + quad*8, s);
  }
  {
    waitflags(fb0, fA, e);
    bf16x8 a0 = *(const bf16x8*)(rd0);
    bf16x8 a1 = *(const bf16x8*)(rd0+32);
    bf16x8 a2 = *(const bf16x8*)(rd0+64);
    bf16x8 a3 = *(const bf16x8*)(rd0+96);
    f32x4 acc[4];
#pragma unroll
    for (int g=0;g<4;++g) acc[g] = __builtin_amdgcn_mfma_f32_16x16x32_bf16(a0, W[g][0], zero4, 0,0,0);
#pragma unroll
    for (int g=0;g<4;++g) acc[g] = __builtin_amdgcn_mfma_f32_16x16x32_bf16(a1, W[g][1], acc[g], 0,0,0);
#pragma unroll
    for (int g=0;g<4;++g) acc[g] = __builtin_amdgcn_mfma_f32_16x16x32_bf16(a2, W[g][2], acc[g], 0,0,0);
#pragma unroll
    for (int g=0;g<4;++g) acc[g] = __builtin_amdgcn_mfma_f32_16x16x32_bf16(a3, W[g][3], acc[g], 0,0,0);
    act(acc, wr0, false);
    publish(pub0);
    fB = rdflags(fb1);
  }

  // steps >=1: W = (dWih + dWhh)
#pragma unroll
  for (int g=0;g<4;++g){
    int n = g*128 + col;
    float s = (g==2) ? 2.f*LOG2E : LOG2E;
#pragma unroll
    for (int m=0;m<4;++m){
      const float* pa = dWih + (size_t)n*Hsz + m*32 + quad*8;
      const float* pb = dWhh + (size_t)n*Hsz + m*32 + quad*8;
      W[g][m] = ldws(pa, pb, s);
    }
  }
  const int nf = (wv >= 6) ? (wv-6)*16 + c16 : 0;
  float* fp = big + quad*(Ssz*Isz) + nf;     // frame(t-1) slot, +32/step

  auto dbody = [&](const unsigned short* rd, const volatile unsigned* fbT, u32x4 fpre, unsigned req,
                   unsigned short* wp, unsigned* pub, const volatile unsigned* fbN, float*& fpp)->u32x4 {
    waitflags(fbT, fpre, req);
    bf16x8 a0 = *(const bf16x8*)(rd);
    bf16x8 a1 = *(const bf16x8*)(rd+32);
    bf16x8 a2 = *(const bf16x8*)(rd+64);
    bf16x8 a3 = *(const bf16x8*)(rd+96);
    f32x4 acc[4];
#pragma unroll
    for (int g=0;g<4;++g) acc[g] = __builtin_amdgcn_mfma_f32_16x16x32_bf16(a0, W[g][0], zero4, 0,0,0);
#pragma unroll
    for (int g=0;g<4;++g) acc[g] = __builtin_amdgcn_mfma_f32_16x16x32_bf16(a1, W[g][1], acc[g], 0,0,0);
#pragma unroll
    for (int g=0;g<4;++g) acc[g] = __builtin_amdgcn_mfma_f32_16x16x32_bf16(a2, W[g][2], acc[g], 0,0,0);
#pragma unroll
    for (int g=0;g<4;++g) acc[g] = __builtin_amdgcn_mfma_f32_16x16x32_bf16(a3, W[g][3], acc[g], 0,0,0);
    act(acc, wp, false);
    publish(pub);
    if (wv >= 6){                            // fc after publish: tail filler
      f32x4 fa = __builtin_amdgcn_mfma_f32_16x16x32_bf16(a0, wf[0], biasf4, 0,0,0);
      fa = __builtin_amdgcn_mfma_f32_16x16x32_bf16(a1, wf[1], fa, 0,0,0);
      fa = __builtin_amdgcn_mfma_f32_16x16x32_bf16(a2, wf[2], fa, 0,0,0);
      fa = __builtin_amdgcn_mfma_f32_16x16x32_bf16(a3, wf[3], fa, 0,0,0);
      if (quad < 2) *fpp = fa[0];
    }
    fpp += 32;
    return rdflags(fbN);
  };

  // t = 1..510 in pairs, then t = 511
  for (int it=0; it<255; ++it){
    fA = dbody(rd1, fb1, fB, e+2, wr1, pub1, fb0, fp);   // odd t reads buf1
    fB = dbody(rd0, fb0, fA, e+2, wr0, pub0, fb1, fp);   // even t reads buf0
    e += 2;
  }
  fA = dbody(rd1, fb1, fB, e+2, wr1, pub1, fb0, fp);     // t=511 -> h(511) in buf0
  e += 2;                                                // e = 1024

  // epilogue: frame 511 from h(511) (buf0)
  if (wv >= 6){
    waitflags(fb0, fA, e);
    bf16x8 a0 = *(const bf16x8*)(rd0);
    bf16x8 a1 = *(const bf16x8*)(rd0+32);
    bf16x8 a2 = *(const bf16x8*)(rd0+64);
    bf16x8 a3 = *(const bf16x8*)(rd0+96);
    f32x4 fa = __builtin_amdgcn_mfma_f32_16x16x32_bf16(a0, wf[0], biasf4, 0,0,0);
    fa = __builtin_amdgcn_mfma_f32_16x16x32_bf16(a1, wf[1], fa, 0,0,0);
    fa = __builtin_amdgcn_mfma_f32_16x16x32_bf16(a2, wf[2], fa, 0,0,0);
    fa = __builtin_amdgcn_mfma_f32_16x16x32_bf16(a3, wf[3], fa, 0,0,0);
    if (quad < 2) *fp = fa[0];
  }
  __syncthreads();

  // bulk coalesced frame store
#pragma unroll 2
  for (int i = tid*4; i < 2*Ssz*Isz; i += NT*4){
    f32x4 v = *(const f32x4*)(big + i);
    *(f32x4*)(out + (size_t)(bg0 + (i>>14))*(Ssz*Isz) + (i & 16383)) = v;
  }
}

extern "C" void kernel_launch(void* const* d_in, const int* in_sizes, int n_in,
                              void* d_out, int out_size, void* d_ws, size_t ws_size,
                              hipStream_t stream) {
  const float* x    = (const float*)d_in[0];
  const float* eWih = (const float*)d_in[1];
  const float* eWhh = (const float*)d_in[2];
  const float* ebih = (const float*)d_in[3];
  const float* ebhh = (const float*)d_in[4];
  const float* dWih = (const float*)d_in[5];
  const float* dWhh = (const float*)d_in[6];
  const float* dbih = (const float*)d_in[7];
  const float* dbhh = (const float*)d_in[8];
  const float* fcW  = (const float*)d_in[9];
  const float* fcb  = (const float*)d_in[10];
  float* outp = (float*)d_out;
  (void)d_ws; (void)ws_size; (void)in_sizes; (void)n_in; (void)out_size;
  lstm_ae<<<dim3(Bsz/BB), dim3(NT), 0, stream>>>(
      x, eWih, eWhh, ebih, ebhh, dWih, dWhh, dbih, dbhh, fcW, fcb, outp);
}